// Round 19
// baseline (146.114 us; speedup 1.0000x reference)
//
#include <hip/hip_runtime.h>

typedef __attribute__((ext_vector_type(8))) _Float16 half8;
typedef __attribute__((ext_vector_type(2))) __fp16 fp16x2;
typedef __attribute__((ext_vector_type(4))) float f32x4;

#define XDIM 8192
#define XOUT 8191
#define TPW 16                     // tiles (of 16 positions) per wave
#define NTILES (1024 * 512)        // 512 tiles per row, 1024 rows
#define NBLOCKS (NTILES / TPW / 4) // 4 waves per block

// ws/LDS layout (per 64 lane-roles, 16B quads, frag-major):
//   [0..5120)      A1_L   at L*1024      + lane*16   (half8, [Whi|Whi])
//   [5120..10240)  A2_L   at (5+L)*1024  + lane*16   (half8, [Wlo|0])
//   [10240..15360) biasL  at 10240+L*1024+ lane*16   (f32x4, C-init)
//   [15360..19456) Fq     at 15360+q*1024+ lane*16   (float4: fw0,fw1,fb,wl)
#define WS_BYTES 19456

union H8 {
    fp16x2 p[4];
    half8 v;
};

#define MFMA32(A, B, C) __builtin_amdgcn_mfma_f32_16x16x32_f16((A), (B), (C), 0, 0, 0)

// One wave precomputes prepared fragments (r12-verified hi/lo split math).
__global__ __launch_bounds__(64) void cnn_prep_kernel(
    const float* __restrict__ w0, const float* __restrict__ b0,
    const float* __restrict__ Wh, const float* __restrict__ bh,
    const float* __restrict__ Wl, void* __restrict__ ws) {
    const int lane = threadIdx.x & 63;
    const int lm = lane & 15;
    const int kb = (lane >> 4) * 4;

    half8* wsA = (half8*)ws;
    f32x4* wsB = (f32x4*)((char*)ws + 10240);
    float4* wsF = (float4*)((char*)ws + 15360);

    for (int L = 0; L < 5; ++L) {
        float _w0 = (lm < 15 && kb + 0 < 15) ? Wh[L*225 + lm*15 + kb + 0] : 0.f;
        float _w1 = (lm < 15 && kb + 1 < 15) ? Wh[L*225 + lm*15 + kb + 1] : 0.f;
        float _w2 = (lm < 15 && kb + 2 < 15) ? Wh[L*225 + lm*15 + kb + 2] : 0.f;
        float _w3 = (lm < 15 && kb + 3 < 15) ? Wh[L*225 + lm*15 + kb + 3] : 0.f;
        fp16x2 h01 = __builtin_amdgcn_cvt_pkrtz(_w0, _w1);
        fp16x2 h23 = __builtin_amdgcn_cvt_pkrtz(_w2, _w3);
        const float e0 = fmaf(-1.0f, (float)h01.x, _w0);
        const float e1 = fmaf(-1.0f, (float)h01.y, _w1);
        const float e2 = fmaf(-1.0f, (float)h23.x, _w2);
        const float e3 = fmaf(-1.0f, (float)h23.y, _w3);
        fp16x2 l01 = __builtin_amdgcn_cvt_pkrtz(e0, e1);
        fp16x2 l23 = __builtin_amdgcn_cvt_pkrtz(e2, e3);
        H8 u1, u2;
        u1.p[0] = h01; u1.p[1] = h23; u1.p[2] = h01; u1.p[3] = h23;   // [Whi|Whi]
        fp16x2 z = __builtin_amdgcn_cvt_pkrtz(0.f, 0.f);
        u2.p[0] = l01; u2.p[1] = l23; u2.p[2] = z;   u2.p[3] = z;     // [Wlo|0]
        wsA[L*64 + lane] = u1.v;
        wsA[(5+L)*64 + lane] = u2.v;

        f32x4 bv;
        bv.x = (kb + 0 < 15) ? bh[L*15 + kb + 0] : 0.f;
        bv.y = (kb + 1 < 15) ? bh[L*15 + kb + 1] : 0.f;
        bv.z = (kb + 2 < 15) ? bh[L*15 + kb + 2] : 0.f;
        bv.w = (kb + 3 < 15) ? bh[L*15 + kb + 3] : 0.f;
        wsB[L*64 + lane] = bv;
    }

    float4 f0, f1, f2, f3;
    f0.x = (kb+0 < 15) ? w0[2*(kb+0)]   : 0.f;
    f0.y = (kb+1 < 15) ? w0[2*(kb+1)]   : 0.f;
    f0.z = (kb+2 < 15) ? w0[2*(kb+2)]   : 0.f;
    f0.w = (kb+3 < 15) ? w0[2*(kb+3)]   : 0.f;
    f1.x = (kb+0 < 15) ? w0[2*(kb+0)+1] : 0.f;
    f1.y = (kb+1 < 15) ? w0[2*(kb+1)+1] : 0.f;
    f1.z = (kb+2 < 15) ? w0[2*(kb+2)+1] : 0.f;
    f1.w = (kb+3 < 15) ? w0[2*(kb+3)+1] : 0.f;
    f2.x = (kb+0 < 15) ? b0[kb+0] : 0.f;
    f2.y = (kb+1 < 15) ? b0[kb+1] : 0.f;
    f2.z = (kb+2 < 15) ? b0[kb+2] : 0.f;
    f2.w = (kb+3 < 15) ? b0[kb+3] : 0.f;
    f3.x = (kb+0 < 15) ? Wl[kb+0] : 0.f;
    f3.y = (kb+1 < 15) ? Wl[kb+1] : 0.f;
    f3.z = (kb+2 < 15) ? Wl[kb+2] : 0.f;
    f3.w = (kb+3 < 15) ? Wl[kb+3] : 0.f;
    wsF[0*64 + lane] = f0;
    wsF[1*64 + lane] = f1;
    wsF[2*64 + lane] = f2;
    wsF[3*64 + lane] = f3;
}

__global__ __attribute__((amdgpu_flat_work_group_size(256, 256)))
void cnn_mfma_kernel(
    const float* __restrict__ rho, const float* __restrict__ bl,
    const void* __restrict__ ws, float* __restrict__ out) {
    // Prepared fragments live in LDS: a reload is ONE ds_read_b128 off a
    // single loop-invariant base VGPR (lane*16) + immediate offset — zero
    // address VALU. Whether the allocator hoists them to registers or
    // re-reads per tile, both outcomes are cheap (DS pipe is otherwise idle).
    __shared__ char lds[WS_BYTES];
    const int tid = threadIdx.x;
    {
        const float4* src = (const float4*)ws;
        float4* dst = (float4*)lds;
        for (int i = tid; i < WS_BYTES / 16; i += 256) dst[i] = src[i];
    }
    __syncthreads();

    const int lane = tid & 63;
    const int lm = lane & 15;          // B-col (position) / D-col
    const char* lbase = lds + lane * 16;

    const float bl0 = bl[0];

    // ---- each wave owns 16 consecutive tiles of one row ----
    const int wid = blockIdx.x * 4 + (tid >> 6);           // 0..32767
    const int brow = wid >> 5;                             // 32 waves per row
    const int xb = ((wid & 31) << 8) + lm;                 // + t*16
    const float* rrow = rho + (size_t)brow * XDIM;
    float* orow = out + (size_t)brow * XOUT;

#pragma unroll 2
    for (int t = 0; t < TPW; ++t) {
        const int x = xb + t * 16;                 // <= 8191
        const float r0 = rrow[x];
        const float r1 = rrow[(x < XDIM - 1) ? x + 1 : XDIM - 1];

        const float4 F0 = *(const float4*)(lbase + 15360 + 0*1024);  // fw0
        const float4 F1 = *(const float4*)(lbase + 15360 + 1*1024);  // fw1
        const float4 F2 = *(const float4*)(lbase + 15360 + 2*1024);  // fb

        // first conv (k=2) + relu (channel 15 slots are zeroed weights -> 0)
        float h0 = fmaxf(fmaf(F0.x, r0, fmaf(F1.x, r1, F2.x)), 0.f);
        float h1 = fmaxf(fmaf(F0.y, r0, fmaf(F1.y, r1, F2.y)), 0.f);
        float h2 = fmaxf(fmaf(F0.z, r0, fmaf(F1.z, r1, F2.z)), 0.f);
        float h3 = fmaxf(fmaf(F0.w, r0, fmaf(F1.w, r1, F2.w)), 0.f);

        // Per layer: B = [hhi|hlo] natural order; D = A1*B + A2*B + bias(C).
#define HLAYER(L)                                                     \
        {                                                             \
            const half8 _A1 = *(const half8*)(lbase + (L)*1024);      \
            const half8 _A2 = *(const half8*)(lbase + (5+(L))*1024);  \
            const f32x4 _BV = *(const f32x4*)(lbase + 10240 + (L)*1024); \
            H8 _b;                                                    \
            _b.p[0] = __builtin_amdgcn_cvt_pkrtz(h0, h1);             \
            _b.p[1] = __builtin_amdgcn_cvt_pkrtz(h2, h3);             \
            const float _e0 = fmaf(-1.0f, (float)_b.p[0].x, h0);      \
            const float _e1 = fmaf(-1.0f, (float)_b.p[0].y, h1);      \
            const float _e2 = fmaf(-1.0f, (float)_b.p[1].x, h2);      \
            const float _e3 = fmaf(-1.0f, (float)_b.p[1].y, h3);      \
            _b.p[2] = __builtin_amdgcn_cvt_pkrtz(_e0, _e1);           \
            _b.p[3] = __builtin_amdgcn_cvt_pkrtz(_e2, _e3);           \
            f32x4 _acc = MFMA32(_A1, _b.v, _BV);                      \
            _acc = MFMA32(_A2, _b.v, _acc);                           \
            h0 = fmaxf(_acc.x, 0.f);                                  \
            h1 = fmaxf(_acc.y, 0.f);                                  \
            h2 = fmaxf(_acc.z, 0.f);                                  \
            h3 = fmaxf(_acc.w, 0.f);                                  \
        }
        HLAYER(0)
        HLAYER(1)
        HLAYER(2)
        HLAYER(3)
        HLAYER(4)
#undef HLAYER

        // final dot (wl slot 15 = 0) + butterfly over 4 lane groups + clip
        const float4 F3 = *(const float4*)(lbase + 15360 + 3*1024);  // wl
        float s = fmaf(F3.x, h0, fmaf(F3.y, h1, fmaf(F3.z, h2, F3.w * h3)));
        s += __shfl_xor(s, 16, 64);
        s += __shfl_xor(s, 32, 64);
        const float y = fminf(fmaxf(s + bl0, 0.f), 1.f);
        if (lane < 16 && x < XOUT) orow[x] = y;
    }
}

extern "C" void kernel_launch(void* const* d_in, const int* in_sizes, int n_in,
                              void* d_out, int out_size, void* d_ws, size_t ws_size,
                              hipStream_t stream) {
    const float* rho = (const float*)d_in[0];
    const float* w0  = (const float*)d_in[1];
    const float* b0  = (const float*)d_in[2];
    const float* Wh  = (const float*)d_in[3];
    const float* bh  = (const float*)d_in[4];
    const float* Wl  = (const float*)d_in[5];
    const float* bl  = (const float*)d_in[6];
    float* out = (float*)d_out;

    cnn_prep_kernel<<<1, 64, 0, stream>>>(w0, b0, Wh, bh, Wl, d_ws);
    cnn_mfma_kernel<<<NBLOCKS, 256, 0, stream>>>(rho, bl, d_ws, out);
}